// Round 6
// baseline (294.222 us; speedup 1.0000x reference)
//
#include <hip/hip_runtime.h>

#define NB  32
#define NC  256
#define NCQ 64
#define WHT 4096                  // 64*64 spatial
#define DQK ((size_t)NCQ * WHT)   // 262144
#define MV  ((size_t)NC * WHT)    // 1048576

typedef __attribute__((ext_vector_type(8))) short short8;
typedef __attribute__((ext_vector_type(4))) float f32x4;
typedef __attribute__((ext_vector_type(2))) float f32x2;
typedef unsigned short ushort_t;

__device__ __forceinline__ ushort_t bf16_rne(float f) {
    union { float f; unsigned u; } v; v.f = f;
    unsigned r = (v.u + 0x7fffu + ((v.u >> 16) & 1u)) >> 16;
    return (ushort_t)r;
}
__device__ __forceinline__ float bf16_f(ushort_t h) {
    union { unsigned u; float f; } v; v.u = ((unsigned)h) << 16; return v.f;
}

// fragment-order offset within one 64x256 W tile (elements):
// value W[r][kk] lands at (kb=kk>>5)*2048 + lh*512 + m*128 + ll*8 + e
__device__ __forceinline__ int frag_off(int r, int kk) {
    return ((kk >> 5) * 16 + ((kk >> 3) & 3) * 4 + (r >> 4)) * 128
           + (r & 15) * 8 + (kk & 7);
}

// ---------------------------------------------------------------------------
// P: convert weights to bf16 hi (+lo for q/k), permuted to MFMA fragment order
// ---------------------------------------------------------------------------
__global__ __launch_bounds__(256)
void prep_w(const float* __restrict__ Wq, const float* __restrict__ Wk,
            const float* __restrict__ Wv,
            ushort_t* __restrict__ wv_hi,
            ushort_t* __restrict__ wq_hi, ushort_t* __restrict__ wq_lo,
            ushort_t* __restrict__ wk_hi, ushort_t* __restrict__ wk_lo)
{
    int i = blockIdx.x * 256 + threadIdx.x;
    if (i < 65536) {                       // Wv: 256 rows -> 4 tiles of 64
        int R = i >> 8, kk = i & 255;
        wv_hi[(R >> 6) * 16384 + frag_off(R & 63, kk)] = bf16_rne(Wv[i]);
    } else if (i < 81920) {                // Wq: 64 rows
        int j = i - 65536; int r = j >> 8, kk = j & 255;
        float f = Wq[j]; ushort_t h = bf16_rne(f);
        int o = frag_off(r, kk);
        wq_hi[o] = h; wq_lo[o] = bf16_rne(f - bf16_f(h));
    } else if (i < 98304) {                // Wk: 64 rows
        int j = i - 81920; int r = j >> 8, kk = j & 255;
        float f = Wk[j]; ushort_t h = bf16_rne(f);
        int o = frag_off(r, kk);
        wk_hi[o] = h; wk_lo[o] = bf16_rne(f - bf16_f(h));
    }
}

// load next-kb B tile (2 n-groups x 8 k-elems) into register buffer
#define LOADB(dst, kbv) do {                                            \
    const float* xk_ = xw + (size_t)(kbv) * 32 * WHT;                   \
    _Pragma("unroll") for (int n_ = 0; n_ < 2; ++n_)                    \
    _Pragma("unroll") for (int e_ = 0; e_ < 8; ++e_)                    \
        dst[n_][e_] = xk_[(size_t)e_ * WHT + n_ * 16];                  \
} while (0)

// pack 8 floats -> 8 bf16 (truncate to top 16 bits) via v_perm
#define PACK_HI(dst, src) do {                                          \
    union { unsigned u[4]; short8 s; } pk_;                             \
    _Pragma("unroll") for (int p_ = 0; p_ < 4; ++p_)                    \
        pk_.u[p_] = __builtin_amdgcn_perm(                              \
            __float_as_uint(src[2 * p_ + 1]),                           \
            __float_as_uint(src[2 * p_]), 0x07060302u);                 \
    dst = pk_.s;                                                        \
} while (0)

// ---------------------------------------------------------------------------
// K1a: v projection (hi-only). 32 KB LDS -> 4 blocks/CU, 100% occupancy cap.
// Block = 512 threads = 8 waves; block tile 64 rows x 256 spatial; per-wave
// tile 64x32. W fragments staged to LDS once; B (x) loads double-buffered.
// ---------------------------------------------------------------------------
__global__ __launch_bounds__(512, 8)
void v_mfma(const float* __restrict__ x0,
            const ushort_t* __restrict__ wv_hi,
            const float* __restrict__ bv,
            ushort_t* __restrict__ vbf)
{
    __shared__ ushort_t lds_hi[16384];   // 32 KB, fragment order

    const int t   = threadIdx.x;
    const int bid = blockIdx.x;
    // bid -> (b, nt, mt 0..3): all 4 v-tiles of one (b,nt) panel on one XCD
    const int xcd = bid & 7;
    const int sl  = bid >> 3;            // 0..255
    const int mt  = sl & 3;
    const int g   = (sl >> 2) * 8 + xcd; // 0..511
    const int nt  = g & 15;
    const int b   = g >> 4;

    const int wave = t >> 6;
    const int lane = t & 63;
    const int lh   = lane >> 4;
    const int ll   = lane & 15;

    const ushort_t* whi = wv_hi + mt * 16384;
#pragma unroll
    for (int r = 0; r < 4; ++r)
        *(short8*)&lds_hi[(r * 512 + t) * 8] = *(const short8*)(whi + (r * 512 + t) * 8);
    __syncthreads();

    const float* xw = x0 + (size_t)b * NC * WHT
                      + nt * 256 + wave * 32 + ll + (size_t)lh * 8 * WHT;
    const int abase = lh * 512 + ll * 8;

    f32x4 acc[4][2];
#pragma unroll
    for (int m = 0; m < 4; ++m)
#pragma unroll
        for (int n = 0; n < 2; ++n) acc[m][n] = (f32x4){0.f, 0.f, 0.f, 0.f};

    float xfA[2][8], xfB[2][8];
    LOADB(xfA, 0);

#pragma unroll
    for (int kb = 0; kb < 8; ++kb) {
        float (*cur)[8] = (kb & 1) ? xfB : xfA;
        float (*nxt)[8] = (kb & 1) ? xfA : xfB;
        if (kb < 7) LOADB(nxt, kb + 1);

        short8 bh[2];
#pragma unroll
        for (int n = 0; n < 2; ++n) PACK_HI(bh[n], cur[n]);

#pragma unroll
        for (int m = 0; m < 4; ++m) {
            short8 a_hi = *(const short8*)&lds_hi[kb * 2048 + abase + m * 128];
#pragma unroll
            for (int n = 0; n < 2; ++n)
                acc[m][n] = __builtin_amdgcn_mfma_f32_16x16x32_bf16(
                    a_hi, bh[n], acc[m][n], 0, 0, 0);
        }
    }

    const int colbase = nt * 256 + wave * 32;
    ushort_t* outp = vbf + ((size_t)b * NC + mt * 64) * WHT + colbase;
    const float* bias = bv + mt * 64;
#pragma unroll
    for (int m = 0; m < 4; ++m)
#pragma unroll
        for (int n = 0; n < 2; ++n)
#pragma unroll
            for (int r = 0; r < 4; ++r) {
                const int row = m * 16 + 4 * lh + r;
                outp[(size_t)row * WHT + n * 16 + ll] =
                    bf16_rne(acc[m][n][r] + bias[row]);
            }
}

// ---------------------------------------------------------------------------
// K1b: q/k projections, 3-pass hi/lo split MFMA. 64 KB LDS -> 2 blocks/CU.
// ---------------------------------------------------------------------------
__global__ __launch_bounds__(512, 4)
void qk_mfma(const float* __restrict__ x0, const float* __restrict__ x1,
             const ushort_t* __restrict__ wq_hi, const ushort_t* __restrict__ wq_lo,
             const ushort_t* __restrict__ wk_hi, const ushort_t* __restrict__ wk_lo,
             const float* __restrict__ bq, const float* __restrict__ bk,
             float* __restrict__ q, float* __restrict__ k)
{
    __shared__ ushort_t lds_hi[16384];   // 32 KB
    __shared__ ushort_t lds_lo[16384];   // 32 KB

    const int t   = threadIdx.x;
    const int bid = blockIdx.x;
    // bid -> (b, nt, mt 0..1): q,k of one (b,nt) panel on one XCD
    const int xcd = bid & 7;
    const int sl  = bid >> 3;            // 0..127
    const int mt  = sl & 1;              // 0=q, 1=k
    const int g   = (sl >> 1) * 8 + xcd; // 0..511
    const int nt  = g & 15;
    const int b   = g >> 4;

    const bool isQ = (mt == 0);

    const int wave = t >> 6;
    const int lane = t & 63;
    const int lh   = lane >> 4;
    const int ll   = lane & 15;

    const ushort_t* whi = isQ ? wq_hi : wk_hi;
    const ushort_t* wlo = isQ ? wq_lo : wk_lo;
#pragma unroll
    for (int r = 0; r < 4; ++r) {
        *(short8*)&lds_hi[(r * 512 + t) * 8] = *(const short8*)(whi + (r * 512 + t) * 8);
        *(short8*)&lds_lo[(r * 512 + t) * 8] = *(const short8*)(wlo + (r * 512 + t) * 8);
    }
    __syncthreads();

    const float* xw = (isQ ? x0 : x1) + (size_t)b * NC * WHT
                      + nt * 256 + wave * 32 + ll + (size_t)lh * 8 * WHT;
    const int abase = lh * 512 + ll * 8;

    f32x4 acc[4][2];
#pragma unroll
    for (int m = 0; m < 4; ++m)
#pragma unroll
        for (int n = 0; n < 2; ++n) acc[m][n] = (f32x4){0.f, 0.f, 0.f, 0.f};

    float xfA[2][8], xfB[2][8];
    LOADB(xfA, 0);

#pragma unroll
    for (int kb = 0; kb < 8; ++kb) {
        float (*cur)[8] = (kb & 1) ? xfB : xfA;
        float (*nxt)[8] = (kb & 1) ? xfA : xfB;
        if (kb < 7) LOADB(nxt, kb + 1);

        short8 bh[2], bl[2];
#pragma unroll
        for (int n = 0; n < 2; ++n) {
            PACK_HI(bh[n], cur[n]);
            float lo[8];
#pragma unroll
            for (int e = 0; e < 8; ++e) {
                float hf = __uint_as_float(__float_as_uint(cur[n][e]) & 0xffff0000u);
                lo[e] = cur[n][e] - hf;
            }
            PACK_HI(bl[n], lo);
        }

#pragma unroll
        for (int m = 0; m < 4; ++m) {
            short8 a_hi = *(const short8*)&lds_hi[kb * 2048 + abase + m * 128];
            short8 a_lo = *(const short8*)&lds_lo[kb * 2048 + abase + m * 128];
#pragma unroll
            for (int n = 0; n < 2; ++n) {
                acc[m][n] = __builtin_amdgcn_mfma_f32_16x16x32_bf16(
                    a_hi, bh[n], acc[m][n], 0, 0, 0);
                acc[m][n] = __builtin_amdgcn_mfma_f32_16x16x32_bf16(
                    a_hi, bl[n], acc[m][n], 0, 0, 0);
                acc[m][n] = __builtin_amdgcn_mfma_f32_16x16x32_bf16(
                    a_lo, bh[n], acc[m][n], 0, 0, 0);
            }
        }
    }

    const int colbase = nt * 256 + wave * 32;
    float* outp = (isQ ? q : k) + (size_t)b * NCQ * WHT + colbase;
    const float* bias = isQ ? bq : bk;
#pragma unroll
    for (int m = 0; m < 4; ++m)
#pragma unroll
        for (int n = 0; n < 2; ++n)
#pragma unroll
            for (int r = 0; r < 4; ++r) {
                const int row = m * 16 + 4 * lh + r;
                outp[(size_t)row * WHT + n * 16 + ll] =
                    acc[m][n][r] + bias[row];
            }
}

// ---------------------------------------------------------------------------
// K2: energy[i,j] = sum_d k[i,d]*q[j,d]  (32x32, K=262144)
// ---------------------------------------------------------------------------
__global__ __launch_bounds__(256)
void energy_kernel(const float* __restrict__ q, const float* __restrict__ k,
                   float* __restrict__ energy)
{
    __shared__ float kt[256][17];
    __shared__ float qt[256][17];

    const int t  = threadIdx.x;
    const int d0 = blockIdx.x * 256;
    const int ih = blockIdx.y;
    const int jh = blockIdx.z;

    for (int r = 0; r < 16; ++r) {
        kt[t][r] = k[(size_t)(ih * 16 + r) * DQK + d0 + t];
        qt[t][r] = q[(size_t)(jh * 16 + r) * DQK + d0 + t];
    }
    __syncthreads();

    const int ii = t >> 4;
    const int jj = t & 15;
    float a0 = 0.f, a1 = 0.f, a2 = 0.f, a3 = 0.f;
#pragma unroll 8
    for (int d = 0; d < 256; d += 4) {
        a0 = fmaf(kt[d + 0][ii], qt[d + 0][jj], a0);
        a1 = fmaf(kt[d + 1][ii], qt[d + 1][jj], a1);
        a2 = fmaf(kt[d + 2][ii], qt[d + 2][jj], a2);
        a3 = fmaf(kt[d + 3][ii], qt[d + 3][jj], a3);
    }

    atomicAdd(&energy[(ih * 16 + ii) * 32 + jh * 16 + jj], (a0 + a1) + (a2 + a3));
}

// ---------------------------------------------------------------------------
// K2b: row softmax of energy [32x32]. 1 block, 1024 threads.
// ---------------------------------------------------------------------------
__global__ __launch_bounds__(1024)
void softmax_kernel(const float* __restrict__ energy,
                    float* __restrict__ att, float* __restrict__ att_out)
{
    const int t = threadIdx.x;
    const int i = t >> 5;
    const int j = t & 31;
    float e = energy[i * 32 + j];
    float m = e;
#pragma unroll
    for (int o = 16; o; o >>= 1) m = fmaxf(m, __shfl_xor(m, o, 32));
    float ex = __expf(e - m);
    float s = ex;
#pragma unroll
    for (int o = 16; o; o >>= 1) s += __shfl_xor(s, o, 32);
    float a = ex / s;
    att[i * 32 + j] = a;
    att_out[i * 32 + j] = a;
}

// ---------------------------------------------------------------------------
// K3: out[i,m] = gamma * sum_j A[i,j]*v[j,m] + x1[i,m]; v is bf16-packed.
// ---------------------------------------------------------------------------
__global__ __launch_bounds__(256)
void out_kernel(const ushort_t* __restrict__ vbf, const float* __restrict__ att,
                const float* __restrict__ x1, const float* __restrict__ gamma,
                float* __restrict__ out)
{
    const int t = threadIdx.x;
    const size_t m0 = (size_t)blockIdx.x * 512 + 2 * t;

    float v0[32], v1[32];
#pragma unroll
    for (int j = 0; j < 32; ++j) {
        unsigned u = *(const unsigned*)(vbf + (size_t)j * MV + m0);
        v0[j] = __uint_as_float(u << 16);
        v1[j] = __uint_as_float(u & 0xffff0000u);
    }

    const float g = gamma[0];
    for (int i = 0; i < 32; ++i) {
        float a0 = 0.f, a1 = 0.f;
#pragma unroll
        for (int j = 0; j < 32; ++j) {
            float w = att[i * 32 + j];
            a0 = fmaf(w, v0[j], a0);
            a1 = fmaf(w, v1[j], a1);
        }
        f32x2 xx = *(const f32x2*)(x1 + (size_t)i * MV + m0);
        f32x2 oo; oo.x = g * a0 + xx.x; oo.y = g * a1 + xx.y;
        *(f32x2*)(out + (size_t)i * MV + m0) = oo;
    }
}

// ---------------------------------------------------------------------------
extern "C" void kernel_launch(void* const* d_in, const int* in_sizes, int n_in,
                              void* d_out, int out_size, void* d_ws, size_t ws_size,
                              hipStream_t stream)
{
    const float* x0    = (const float*)d_in[0];
    const float* x1    = (const float*)d_in[1];
    const float* Wq    = (const float*)d_in[2];
    const float* bq    = (const float*)d_in[3];
    const float* Wk    = (const float*)d_in[4];
    const float* bk    = (const float*)d_in[5];
    const float* Wv    = (const float*)d_in[6];
    const float* bv    = (const float*)d_in[7];
    const float* gamma = (const float*)d_in[8];

    float* ws     = (float*)d_ws;
    float* q      = ws;                                  // 8,388,608 f
    float* k      = q + (size_t)NB * NCQ * WHT;          // 8,388,608 f
    float* energy = k + (size_t)NB * NCQ * WHT;          //     1,024 f
    float* att    = energy + 1024;                       //     1,024 f

    ushort_t* wv_hi = (ushort_t*)(att + 1024);           // 65,536 us (16B-aligned)
    ushort_t* wq_hi = wv_hi + 65536;
    ushort_t* wq_lo = wq_hi + 16384;
    ushort_t* wk_hi = wq_lo + 16384;
    ushort_t* wk_lo = wk_hi + 16384;
    ushort_t* vbf   = wk_lo + 16384;                     // 33,554,432 us

    float* out     = (float*)d_out;
    float* att_out = out + (size_t)NB * NC * WHT;

    hipMemsetAsync(energy, 0, 1024 * sizeof(float), stream);

    prep_w<<<384, 256, 0, stream>>>(Wq, Wk, Wv, wv_hi, wq_hi, wq_lo, wk_hi, wk_lo);
    qk_mfma<<<1024, 512, 0, stream>>>(x0, x1, wq_hi, wq_lo, wk_hi, wk_lo, bq, bk, q, k);
    v_mfma<<<2048, 512, 0, stream>>>(x0, wv_hi, bv, vbf);
    energy_kernel<<<dim3(1024, 2, 2), 256, 0, stream>>>(q, k, energy);
    softmax_kernel<<<1, 1024, 0, stream>>>(energy, att, att_out);
    out_kernel<<<2048, 256, 0, stream>>>(vbf, att, x1, gamma, out);
}

// Round 7
// 264.315 us; speedup vs baseline: 1.1131x; 1.1131x over previous
//
#include <hip/hip_runtime.h>

#define NB  32
#define NC  256
#define NCQ 64
#define WHT 4096                  // 64*64 spatial
#define DQK ((size_t)NCQ * WHT)   // 262144
#define MV  ((size_t)NC * WHT)    // 1048576

typedef __attribute__((ext_vector_type(8))) short short8;
typedef __attribute__((ext_vector_type(4))) float f32x4;
typedef __attribute__((ext_vector_type(2))) float f32x2;
typedef unsigned short ushort_t;

__device__ __forceinline__ ushort_t bf16_rne(float f) {
    union { float f; unsigned u; } v; v.f = f;
    unsigned r = (v.u + 0x7fffu + ((v.u >> 16) & 1u)) >> 16;
    return (ushort_t)r;
}
__device__ __forceinline__ float bf16_f(ushort_t h) {
    union { unsigned u; float f; } v; v.u = ((unsigned)h) << 16; return v.f;
}

// fragment-order offset within one 64x256 W tile (elements):
// value W[r][kk] lands at (kb=kk>>5)*2048 + lh*512 + m*128 + ll*8 + e
__device__ __forceinline__ int frag_off(int r, int kk) {
    return ((kk >> 5) * 16 + ((kk >> 3) & 3) * 4 + (r >> 4)) * 128
           + (r & 15) * 8 + (kk & 7);
}

// ---------------------------------------------------------------------------
// P: convert weights to bf16 hi (+lo for q/k), permuted to MFMA fragment order
// ---------------------------------------------------------------------------
__global__ __launch_bounds__(256)
void prep_w(const float* __restrict__ Wq, const float* __restrict__ Wk,
            const float* __restrict__ Wv,
            ushort_t* __restrict__ wv_hi,
            ushort_t* __restrict__ wq_hi, ushort_t* __restrict__ wq_lo,
            ushort_t* __restrict__ wk_hi, ushort_t* __restrict__ wk_lo)
{
    int i = blockIdx.x * 256 + threadIdx.x;
    if (i < 65536) {                       // Wv: 256 rows -> 4 tiles of 64
        int R = i >> 8, kk = i & 255;
        wv_hi[(R >> 6) * 16384 + frag_off(R & 63, kk)] = bf16_rne(Wv[i]);
    } else if (i < 81920) {                // Wq: 64 rows
        int j = i - 65536; int r = j >> 8, kk = j & 255;
        float f = Wq[j]; ushort_t h = bf16_rne(f);
        int o = frag_off(r, kk);
        wq_hi[o] = h; wq_lo[o] = bf16_rne(f - bf16_f(h));
    } else if (i < 98304) {                // Wk: 64 rows
        int j = i - 81920; int r = j >> 8, kk = j & 255;
        float f = Wk[j]; ushort_t h = bf16_rne(f);
        int o = frag_off(r, kk);
        wk_hi[o] = h; wk_lo[o] = bf16_rne(f - bf16_f(h));
    }
}

// pack 8 floats -> 8 bf16 (truncate to top 16 bits) via v_perm
#define PACK_HI(dst, src) do {                                          \
    union { unsigned u[4]; short8 s; } pk_;                             \
    _Pragma("unroll") for (int p_ = 0; p_ < 4; ++p_)                    \
        pk_.u[p_] = __builtin_amdgcn_perm(                              \
            __float_as_uint(src[2 * p_ + 1]),                           \
            __float_as_uint(src[2 * p_]), 0x07060302u);                 \
    dst = pk_.s;                                                        \
} while (0)

// v path: load 2 n-groups x 8 k-elems of x for k-chunk kbv
#define LOADB2(dst, kbv) do {                                           \
    const float* xk_ = xw + (size_t)(kbv) * 32 * WHT;                   \
    _Pragma("unroll") for (int n_ = 0; n_ < 2; ++n_)                    \
    _Pragma("unroll") for (int e_ = 0; e_ < 8; ++e_)                    \
        dst[n_][e_] = xk_[(size_t)e_ * WHT + n_ * 16];                  \
} while (0)

// qk path: load 1 n-group x 8 k-elems
#define LOADB1(dst, kbv) do {                                           \
    const float* xk_ = xw + (size_t)(kbv) * 32 * WHT;                   \
    _Pragma("unroll") for (int e_ = 0; e_ < 8; ++e_)                    \
        dst[e_] = xk_[(size_t)e_ * WHT];                                \
} while (0)

// v compute for one k-chunk: convert + 8 MFMA (a_hi from LDS)
#define PROCV(buf, kbv) do {                                            \
    short8 bh_[2];                                                      \
    _Pragma("unroll") for (int n_ = 0; n_ < 2; ++n_)                    \
        PACK_HI(bh_[n_], buf[n_]);                                      \
    _Pragma("unroll") for (int m_ = 0; m_ < 4; ++m_) {                  \
        short8 ah_ = *(const short8*)&lds_hi[(kbv) * 2048 + abase + m_ * 128]; \
        _Pragma("unroll") for (int n_ = 0; n_ < 2; ++n_)                \
            acc[m_][n_] = __builtin_amdgcn_mfma_f32_16x16x32_bf16(      \
                ah_, bh_[n_], acc[m_][n_], 0, 0, 0);                    \
    }                                                                   \
} while (0)

// qk compute for one k-chunk: 3-pass hi/lo split (a_hi LDS, a_lo global/L2)
#define PROCQK(buf, kbv) do {                                           \
    short8 bh_, bl_;                                                    \
    PACK_HI(bh_, buf);                                                  \
    float lo_[8];                                                       \
    _Pragma("unroll") for (int e_ = 0; e_ < 8; ++e_) {                  \
        float hf_ = __uint_as_float(__float_as_uint(buf[e_]) & 0xffff0000u); \
        lo_[e_] = buf[e_] - hf_;                                        \
    }                                                                   \
    PACK_HI(bl_, lo_);                                                  \
    _Pragma("unroll") for (int m_ = 0; m_ < 4; ++m_) {                  \
        short8 ah_ = *(const short8*)&lds_hi[(kbv) * 2048 + abase + m_ * 128]; \
        short8 al_ = *(const short8*)(wlo + (kbv) * 2048 + abase + m_ * 128);  \
        acc2[m_] = __builtin_amdgcn_mfma_f32_16x16x32_bf16(ah_, bh_, acc2[m_], 0, 0, 0); \
        acc2[m_] = __builtin_amdgcn_mfma_f32_16x16x32_bf16(ah_, bl_, acc2[m_], 0, 0, 0); \
        acc2[m_] = __builtin_amdgcn_mfma_f32_16x16x32_bf16(al_, bh_, acc2[m_], 0, 0, 0); \
    }                                                                   \
} while (0)

#define SBAR() __builtin_amdgcn_sched_barrier(0)

// ---------------------------------------------------------------------------
// K1: fused q/k/v projections via bf16 MFMA. 512 threads = 8 waves.
// Block slots per (b, nt256) group: 0-3 = v mt (64 rows x 256 sp, 64x32/wave),
// 4,5 = q halves, 6,7 = k halves (64 rows x 128 sp, 64x16/wave).
// 32 KB LDS (hi weights only); qk a_lo from L2-resident global.
// Register double-buffered x prefetch with sched_barrier fences so the
// compiler cannot de-pipeline the loads (R5 failure mode, VGPR=52 proof).
// ---------------------------------------------------------------------------
__global__ __launch_bounds__(512, 4)
void qkv_mfma(const float* __restrict__ x0, const float* __restrict__ x1,
              const ushort_t* __restrict__ wv_hi,
              const ushort_t* __restrict__ wq_hi, const ushort_t* __restrict__ wq_lo,
              const ushort_t* __restrict__ wk_hi, const ushort_t* __restrict__ wk_lo,
              const float* __restrict__ bq, const float* __restrict__ bk,
              const float* __restrict__ bv,
              float* __restrict__ q, float* __restrict__ k,
              ushort_t* __restrict__ vbf)
{
    __shared__ ushort_t lds_hi[16384];   // 32 KB, fragment order

    const int t   = threadIdx.x;
    const int bid = blockIdx.x;
    // bid -> (b, nt, slot): all 8 slots of one (b,nt) panel on one XCD
    const int xcd  = bid & 7;
    const int r0   = bid >> 3;           // 0..511
    const int slot = r0 & 7;
    const int gg   = r0 >> 3;            // 0..63
    const int g    = gg * 8 + xcd;       // 0..511
    const int nt   = g & 15;
    const int b    = g >> 4;

    const bool isV = (slot < 4);

    const int wave = t >> 6;
    const int lane = t & 63;
    const int lh   = lane >> 4;
    const int ll   = lane & 15;

    const ushort_t* whi = isV ? (wv_hi + slot * 16384)
                              : ((slot < 6) ? wq_hi : wk_hi);

    // ---- stage hi-W tile to LDS (linear fragment-order copy) ----
#pragma unroll
    for (int r = 0; r < 4; ++r)
        *(short8*)&lds_hi[(r * 512 + t) * 8] = *(const short8*)(whi + (r * 512 + t) * 8);
    __syncthreads();

    const int abase = lh * 512 + ll * 8;

    if (isV) {
        const float* xw = x0 + (size_t)b * NC * WHT
                          + nt * 256 + wave * 32 + ll + (size_t)lh * 8 * WHT;

        f32x4 acc[4][2];
#pragma unroll
        for (int m = 0; m < 4; ++m)
#pragma unroll
            for (int n = 0; n < 2; ++n) acc[m][n] = (f32x4){0.f, 0.f, 0.f, 0.f};

        float xfA[2][8], xfB[2][8];
        LOADB2(xfA, 0);
        SBAR();
#pragma unroll
        for (int p = 0; p < 4; ++p) {
            LOADB2(xfB, 2 * p + 1);
            SBAR();
            PROCV(xfA, 2 * p);
            if (p < 3) LOADB2(xfA, 2 * p + 2);
            SBAR();
            PROCV(xfB, 2 * p + 1);
            SBAR();
        }

        const int colbase = nt * 256 + wave * 32;
        ushort_t* outp = vbf + ((size_t)b * NC + slot * 64) * WHT + colbase;
        const float* bias = bv + slot * 64;
#pragma unroll
        for (int m = 0; m < 4; ++m)
#pragma unroll
            for (int n = 0; n < 2; ++n)
#pragma unroll
                for (int r = 0; r < 4; ++r) {
                    const int row = m * 16 + 4 * lh + r;
                    outp[(size_t)row * WHT + n * 16 + ll] =
                        bf16_rne(acc[m][n][r] + bias[row]);
                }
    } else {
        const bool isQ  = (slot < 6);
        const int  half = slot & 1;
        const ushort_t* wlo = isQ ? wq_lo : wk_lo;

        const float* xw = (isQ ? x0 : x1) + (size_t)b * NC * WHT
                          + nt * 256 + half * 128 + wave * 16 + ll
                          + (size_t)lh * 8 * WHT;

        f32x4 acc2[4];
#pragma unroll
        for (int m = 0; m < 4; ++m) acc2[m] = (f32x4){0.f, 0.f, 0.f, 0.f};

        float xfA[8], xfB[8];
        LOADB1(xfA, 0);
        SBAR();
#pragma unroll
        for (int p = 0; p < 4; ++p) {
            LOADB1(xfB, 2 * p + 1);
            SBAR();
            PROCQK(xfA, 2 * p);
            if (p < 3) LOADB1(xfA, 2 * p + 2);
            SBAR();
            PROCQK(xfB, 2 * p + 1);
            SBAR();
        }

        const int colbase = nt * 256 + half * 128 + wave * 16;
        float* outp = (isQ ? q : k) + (size_t)b * NCQ * WHT + colbase;
        const float* bias = isQ ? bq : bk;
#pragma unroll
        for (int m = 0; m < 4; ++m)
#pragma unroll
            for (int r = 0; r < 4; ++r) {
                const int row = m * 16 + 4 * lh + r;
                outp[(size_t)row * WHT + ll] = acc2[m][r] + bias[row];
            }
    }
}

// ---------------------------------------------------------------------------
// K2: energy[i,j] = sum_d k[i,d]*q[j,d]  (32x32, K=262144)
// ---------------------------------------------------------------------------
__global__ __launch_bounds__(256)
void energy_kernel(const float* __restrict__ q, const float* __restrict__ k,
                   float* __restrict__ energy)
{
    __shared__ float kt[256][17];
    __shared__ float qt[256][17];

    const int t  = threadIdx.x;
    const int d0 = blockIdx.x * 256;
    const int ih = blockIdx.y;
    const int jh = blockIdx.z;

    for (int r = 0; r < 16; ++r) {
        kt[t][r] = k[(size_t)(ih * 16 + r) * DQK + d0 + t];
        qt[t][r] = q[(size_t)(jh * 16 + r) * DQK + d0 + t];
    }
    __syncthreads();

    const int ii = t >> 4;
    const int jj = t & 15;
    float a0 = 0.f, a1 = 0.f, a2 = 0.f, a3 = 0.f;
#pragma unroll 8
    for (int d = 0; d < 256; d += 4) {
        a0 = fmaf(kt[d + 0][ii], qt[d + 0][jj], a0);
        a1 = fmaf(kt[d + 1][ii], qt[d + 1][jj], a1);
        a2 = fmaf(kt[d + 2][ii], qt[d + 2][jj], a2);
        a3 = fmaf(kt[d + 3][ii], qt[d + 3][jj], a3);
    }

    atomicAdd(&energy[(ih * 16 + ii) * 32 + jh * 16 + jj], (a0 + a1) + (a2 + a3));
}

// ---------------------------------------------------------------------------
// K2b: row softmax of energy [32x32]. 1 block, 1024 threads.
// ---------------------------------------------------------------------------
__global__ __launch_bounds__(1024)
void softmax_kernel(const float* __restrict__ energy,
                    float* __restrict__ att, float* __restrict__ att_out)
{
    const int t = threadIdx.x;
    const int i = t >> 5;
    const int j = t & 31;
    float e = energy[i * 32 + j];
    float m = e;
#pragma unroll
    for (int o = 16; o; o >>= 1) m = fmaxf(m, __shfl_xor(m, o, 32));
    float ex = __expf(e - m);
    float s = ex;
#pragma unroll
    for (int o = 16; o; o >>= 1) s += __shfl_xor(s, o, 32);
    float a = ex / s;
    att[i * 32 + j] = a;
    att_out[i * 32 + j] = a;
}

// ---------------------------------------------------------------------------
// K3: out[i,m] = gamma * sum_j A[i,j]*v[j,m] + x1[i,m]; v is bf16-packed.
// ---------------------------------------------------------------------------
__global__ __launch_bounds__(256)
void out_kernel(const ushort_t* __restrict__ vbf, const float* __restrict__ att,
                const float* __restrict__ x1, const float* __restrict__ gamma,
                float* __restrict__ out)
{
    const int t = threadIdx.x;
    const size_t m0 = (size_t)blockIdx.x * 512 + 2 * t;

    float v0[32], v1[32];
#pragma unroll
    for (int j = 0; j < 32; ++j) {
        unsigned u = *(const unsigned*)(vbf + (size_t)j * MV + m0);
        v0[j] = __uint_as_float(u << 16);
        v1[j] = __uint_as_float(u & 0xffff0000u);
    }

    const float g = gamma[0];
    for (int i = 0; i < 32; ++i) {
        float a0 = 0.f, a1 = 0.f;
#pragma unroll
        for (int j = 0; j < 32; ++j) {
            float w = att[i * 32 + j];
            a0 = fmaf(w, v0[j], a0);
            a1 = fmaf(w, v1[j], a1);
        }
        f32x2 xx = *(const f32x2*)(x1 + (size_t)i * MV + m0);
        f32x2 oo; oo.x = g * a0 + xx.x; oo.y = g * a1 + xx.y;
        *(f32x2*)(out + (size_t)i * MV + m0) = oo;
    }
}

// ---------------------------------------------------------------------------
extern "C" void kernel_launch(void* const* d_in, const int* in_sizes, int n_in,
                              void* d_out, int out_size, void* d_ws, size_t ws_size,
                              hipStream_t stream)
{
    const float* x0    = (const float*)d_in[0];
    const float* x1    = (const float*)d_in[1];
    const float* Wq    = (const float*)d_in[2];
    const float* bq    = (const float*)d_in[3];
    const float* Wk    = (const float*)d_in[4];
    const float* bk    = (const float*)d_in[5];
    const float* Wv    = (const float*)d_in[6];
    const float* bv    = (const float*)d_in[7];
    const float* gamma = (const float*)d_in[8];

    float* ws     = (float*)d_ws;
    float* q      = ws;                                  // 8,388,608 f
    float* k      = q + (size_t)NB * NCQ * WHT;          // 8,388,608 f
    float* energy = k + (size_t)NB * NCQ * WHT;          //     1,024 f
    float* att    = energy + 1024;                       //     1,024 f

    ushort_t* wv_hi = (ushort_t*)(att + 1024);           // 65,536 us (16B-aligned)
    ushort_t* wq_hi = wv_hi + 65536;
    ushort_t* wq_lo = wq_hi + 16384;
    ushort_t* wk_hi = wq_lo + 16384;
    ushort_t* wk_lo = wk_hi + 16384;
    ushort_t* vbf   = wk_lo + 16384;                     // 33,554,432 us

    float* out     = (float*)d_out;
    float* att_out = out + (size_t)NB * NC * WHT;

    hipMemsetAsync(energy, 0, 1024 * sizeof(float), stream);

    prep_w<<<384, 256, 0, stream>>>(Wq, Wk, Wv, wv_hi, wq_hi, wq_lo, wk_hi, wk_lo);
    qkv_mfma<<<4096, 512, 0, stream>>>(x0, x1, wv_hi, wq_hi, wq_lo, wk_hi, wk_lo,
                                       bq, bk, bv, q, k, vbf);
    energy_kernel<<<dim3(1024, 2, 2), 256, 0, stream>>>(q, k, energy);
    softmax_kernel<<<1, 1024, 0, stream>>>(energy, att, att_out);
    out_kernel<<<2048, 256, 0, stream>>>(vbf, att, x1, gamma, out);
}